// Round 4
// baseline (490.918 us; speedup 1.0000x reference)
//
#include <hip/hip_runtime.h>

// network_5299989643808: per-(z,zp) tiny MLP over B observations.
// B=2048, Z=64, IDIM=2, HDIM=4, NOPT=4. Dataset: f32 inputs, f32 outputs.
//   (Evidence: bf16-decode of inputs NaN'd (r1/r2); f32-path finite error 2.574>1
//    impossible under bf16 output decode -> output is f32. r3 analysis.)
// Outputs concat flat: pi [B,Z,Z,4], log_pi [B,Z,Z,4], xi [B,Z,Z,4].

#define ZD 64
#define BD 2048

__device__ __forceinline__ void ld4(const float* __restrict__ p, float* d) {
    float4 v = *reinterpret_cast<const float4*>(p);
    d[0] = v.x; d[1] = v.y; d[2] = v.z; d[3] = v.w;
}

__device__ __forceinline__ void layernorm4(float* h, const float* g, const float* be) {
    float m = (h[0] + h[1] + h[2] + h[3]) * 0.25f;
    float d0 = h[0] - m, d1 = h[1] - m, d2 = h[2] - m, d3 = h[3] - m;
    float v = (d0 * d0 + d1 * d1 + d2 * d2 + d3 * d3) * 0.25f;
    float rs = rsqrtf(v + 1e-5f);
    h[0] = d0 * rs * g[0] + be[0];
    h[1] = d1 * rs * g[1] + be[1];
    h[2] = d2 * rs * g[2] + be[2];
    h[3] = d3 * rs * g[3] + be[3];
}

__global__ __launch_bounds__(256) void net_kernel(
    const float* __restrict__ nt,
    const float* __restrict__ W1,  const float* __restrict__ b1,
    const float* __restrict__ g1,  const float* __restrict__ be1,
    const float* __restrict__ W2,  const float* __restrict__ b2,
    const float* __restrict__ g2,  const float* __restrict__ be2,
    const float* __restrict__ Wpi, const float* __restrict__ bpi,
    const float* __restrict__ Wxi, const float* __restrict__ bxi,
    float* __restrict__ out)
{
    const int t  = blockIdx.x * 256 + threadIdx.x;   // 0 .. B*Z*Z-1
    const int zp = t & 63;
    const int z  = (t >> 6) & 63;
    const int b  = t >> 12;
    const int p  = z * ZD + zp;                      // (z,zp) pair index

    const float x0 = nt[b * ZD + z];
    const float x1 = nt[b * ZD + zp];

    // ---- layer 1: 2 -> 4, tanh, LN ----
    float w1a[4], w1b[4], bb[4], gg[4], bbe[4];
    ld4(W1 + p * 8,     w1a);     // W1[z,zp,0,:]
    ld4(W1 + p * 8 + 4, w1b);     // W1[z,zp,1,:]
    ld4(b1  + p * 4, bb);
    ld4(g1  + p * 4, gg);
    ld4(be1 + p * 4, bbe);

    float h[4];
    #pragma unroll
    for (int i = 0; i < 4; ++i)
        h[i] = tanhf(x0 * w1a[i] + x1 * w1b[i] + bb[i]);
    layernorm4(h, gg, bbe);

    // ---- layer 2: 4 -> 4, tanh, LN ----
    float w2[16];
    #pragma unroll
    for (int i = 0; i < 4; ++i) ld4(W2 + p * 16 + i * 4, w2 + i * 4);
    ld4(b2  + p * 4, bb);
    ld4(g2  + p * 4, gg);
    ld4(be2 + p * 4, bbe);

    float h2[4];
    #pragma unroll
    for (int k = 0; k < 4; ++k) {
        float a = bb[k];
        #pragma unroll
        for (int i = 0; i < 4; ++i) a += h[i] * w2[i * 4 + k];
        h2[k] = tanhf(a);
    }
    layernorm4(h2, gg, bbe);

    // ---- heads ----
    float wp[16], bp[4], wx[16], bx[4];
    #pragma unroll
    for (int i = 0; i < 4; ++i) {
        ld4(Wpi + p * 16 + i * 4, wp + i * 4);
        ld4(Wxi + p * 16 + i * 4, wx + i * 4);
    }
    ld4(bpi + p * 4, bp);
    ld4(bxi + p * 4, bx);

    float l[4], q[4];
    #pragma unroll
    for (int o = 0; o < 4; ++o) { l[o] = bp[o]; q[o] = bx[o]; }
    #pragma unroll
    for (int k = 0; k < 4; ++k) {
        #pragma unroll
        for (int o = 0; o < 4; ++o) {
            l[o] += h2[k] * wp[k * 4 + o];
            q[o] += h2[k] * wx[k * 4 + o];
        }
    }

    // ---- log-softmax / pi / sigmoid ----
    float mx = fmaxf(fmaxf(l[0], l[1]), fmaxf(l[2], l[3]));
    float e[4], s = 0.0f;
    #pragma unroll
    for (int o = 0; o < 4; ++o) { e[o] = expf(l[o] - mx); s += e[o]; }
    float inv_s = 1.0f / s;
    float ls = logf(s);

    float4 ppi, plp, pxi;
    ppi.x = e[0] * inv_s; ppi.y = e[1] * inv_s;
    ppi.z = e[2] * inv_s; ppi.w = e[3] * inv_s;
    plp.x = (l[0] - mx) - ls; plp.y = (l[1] - mx) - ls;
    plp.z = (l[2] - mx) - ls; plp.w = (l[3] - mx) - ls;
    pxi.x = 1.0f / (1.0f + expf(-q[0]));
    pxi.y = 1.0f / (1.0f + expf(-q[1]));
    pxi.z = 1.0f / (1.0f + expf(-q[2]));
    pxi.w = 1.0f / (1.0f + expf(-q[3]));

    const size_t OFF = (size_t)BD * ZD * ZD * 4;
    const size_t gi  = (size_t)t * 4;
    *reinterpret_cast<float4*>(out + gi)           = ppi;
    *reinterpret_cast<float4*>(out + OFF + gi)     = plp;
    *reinterpret_cast<float4*>(out + 2 * OFF + gi) = pxi;
}

extern "C" void kernel_launch(void* const* d_in, const int* in_sizes, int n_in,
                              void* d_out, int out_size, void* d_ws, size_t ws_size,
                              hipStream_t stream) {
    const float* nt  = (const float*)d_in[0];
    const float* W1  = (const float*)d_in[1];
    const float* b1  = (const float*)d_in[2];
    const float* g1  = (const float*)d_in[3];
    const float* be1 = (const float*)d_in[4];
    const float* W2  = (const float*)d_in[5];
    const float* b2  = (const float*)d_in[6];
    const float* g2  = (const float*)d_in[7];
    const float* be2 = (const float*)d_in[8];
    const float* Wpi = (const float*)d_in[9];
    const float* bpi = (const float*)d_in[10];
    const float* Wxi = (const float*)d_in[11];
    const float* bxi = (const float*)d_in[12];
    float* out = (float*)d_out;

    const int total = BD * ZD * ZD;          // 8,388,608 threads
    dim3 grid(total / 256), block(256);
    net_kernel<<<grid, block, 0, stream>>>(nt, W1, b1, g1, be1, W2, b2, g2, be2,
                                           Wpi, bpi, Wxi, bxi, out);
}